// Round 8
// baseline (269.261 us; speedup 1.0000x reference)
//
#include <hip/hip_runtime.h>
#include <math.h>

#define NN   20000
#define NE   320000
#define ET   (NE + NN)
#define CPAD 16
#define D_IN 256
#define DHID 512    // H * DH = H * DOUT
#define NLR  1024   // combined l|r width
#define MPAD 20096  // 157 * 128

typedef __attribute__((ext_vector_type(8))) short bf16x8;
typedef __attribute__((ext_vector_type(4))) float f32x4;

typedef __attribute__((address_space(3))) uint       lds_uint;
typedef __attribute__((address_space(1))) const uint gbl_uint;
#define ASYNC16(gp, lp) \
    __builtin_amdgcn_global_load_lds((gbl_uint*)(gp), (lds_uint*)(lp), 16, 0, 0)

__device__ __forceinline__ ushort f2bf(float f) {
    uint u = __float_as_uint(f);
    return (ushort)((u + 0x7fffu + ((u >> 16) & 1u)) >> 16);
}

// ---------------- CSR build ----------------

__global__ __launch_bounds__(256) void init_count(int* count, int* csr_src) {
    int i = blockIdx.x * 256 + threadIdx.x;
    if (i < NN) count[i] = 1;  // self-loop
    if (i < CPAD) csr_src[ET + i] = 0;
}

__global__ __launch_bounds__(256) void hist_kernel(const int* __restrict__ dstv,
                                                   int* __restrict__ count) {
    int e = blockIdx.x * 256 + threadIdx.x;
    if (e < NE) atomicAdd(&count[dstv[e]], 1);
}

__global__ __launch_bounds__(1024) void scan_kernel(const int* __restrict__ count,
                                                    int* __restrict__ offs,
                                                    int* __restrict__ cursor) {
    __shared__ int sm[1024];
    const int CH = 20;
    int t = threadIdx.x;
    int base = t * CH;
    int local[CH];
    int s = 0;
#pragma unroll
    for (int i = 0; i < CH; i++) {
        int idx = base + i;
        int v = (idx < NN) ? count[idx] : 0;
        local[i] = s;
        s += v;
    }
    sm[t] = s;
    __syncthreads();
    for (int o = 1; o < 1024; o <<= 1) {
        int v = (t >= o) ? sm[t - o] : 0;
        __syncthreads();
        sm[t] += v;
        __syncthreads();
    }
    int pref = (t > 0) ? sm[t - 1] : 0;
#pragma unroll
    for (int i = 0; i < CH; i++) {
        int idx = base + i;
        if (idx < NN) {
            int o_ = pref + local[i];
            offs[idx] = o_;
            cursor[idx] = o_;
        }
    }
    if (t == 1023) offs[NN] = sm[1023];
}

__global__ __launch_bounds__(256) void scatter_kernel(const int* __restrict__ srcv,
                                                      const int* __restrict__ dstv,
                                                      int* __restrict__ cursor,
                                                      int* __restrict__ csr_src) {
    int e = blockIdx.x * 256 + threadIdx.x;
    if (e >= ET) return;
    int s, d;
    if (e < NE) { s = srcv[e]; d = dstv[e]; }
    else        { s = e - NE;  d = s; }
    int pos = atomicAdd(&cursor[d], 1);
    csr_src[pos] = s;
}

// ---------------- merged pre-pass: x->bf16 [MPAD,256] + zero pad of [MPAD,512] view ----------------

#define N1Q ((long)MPAD * D_IN / 4)
#define N2Q ((long)(MPAD - NN) * DHID / 4)

__global__ __launch_bounds__(256) void prep_a(const float* __restrict__ x,
                                              ushort* __restrict__ a) {
    long t = (long)blockIdx.x * 256 + threadIdx.x;
    if (t < N1Q) {
        long e = t * 4;
        int row = (int)(e >> 8);
        float4 v = make_float4(0.f, 0.f, 0.f, 0.f);
        if (row < NN) v = *(const float4*)&x[e];
        ushort4 o;
        o.x = f2bf(v.x); o.y = f2bf(v.y); o.z = f2bf(v.z); o.w = f2bf(v.w);
        *(ushort4*)&a[e] = o;
    } else if (t < N1Q + N2Q) {
        long e = (t - N1Q) * 4 + (long)NN * DHID;
        ushort4 z = {0, 0, 0, 0};
        *(ushort4*)&a[e] = z;
    }
}

// ---------------- merged weight transpose: both layers via blockIdx.z ----------------

__global__ __launch_bounds__(256) void transpose_w2(const float* __restrict__ Wl1,
                                                    const float* __restrict__ Wr1,
                                                    ushort* __restrict__ Wt1,
                                                    const float* __restrict__ Wl2,
                                                    const float* __restrict__ Wr2,
                                                    ushort* __restrict__ Wt2) {
    __shared__ float tile[32][33];
    int z = blockIdx.z;
    int K = z ? DHID : D_IN;
    int k0 = blockIdx.x * 32;
    if (k0 >= K) return;
    int n0 = blockIdx.y * 32;
    int tx = threadIdx.x & 31, ty = threadIdx.x >> 5;
    const float* __restrict__ W = (n0 < DHID) ? (z ? Wl2 : Wl1) : (z ? Wr2 : Wr1);
    ushort* __restrict__ Wt = z ? Wt2 : Wt1;
    int nb = (n0 < DHID) ? n0 : n0 - DHID;
#pragma unroll
    for (int r = ty; r < 32; r += 8)
        tile[r][tx] = W[(long)(k0 + r) * DHID + nb + tx];
    __syncthreads();
#pragma unroll
    for (int r = ty; r < 32; r += 8)
        Wt[(long)(n0 + r) * K + k0 + tx] = f2bf(tile[tx][r]);
}

// ---------------- bf16 MFMA GEMM: out[M,1024] = A[M,K] @ Wt^T + (bl|br) ----------------
// Operand-SWAPPED mfma (bfr, af) -> acc holds C^T fragments:
//   C-row  = row0 + wr*64 + m*16 + (lane&15)
//   C-cols = col0 + wc*64 + n*16 + (lane>>4)*4 + {0..3}   (4 consecutive!)
// -> epilogue stores ushort4 (8B) per fragment instead of 4 scalar ushorts.

#define BM 128
#define BN 128
#define BK 64

__global__ __launch_bounds__(256) void gemm_mfma(const ushort* __restrict__ A, int K,
                                                 const ushort* __restrict__ Wt,
                                                 const float* __restrict__ bl,
                                                 const float* __restrict__ br,
                                                 ushort* __restrict__ out) {
    __shared__ ushort As[BM * BK];
    __shared__ ushort Bs[BN * BK];

    int t = threadIdx.x;
    int row0 = blockIdx.x * BM;
    int col0 = blockIdx.y * BN;

    int lane = t & 63, w = t >> 6;
    int wr = w >> 1, wc = w & 1;
    int l16 = lane & 15, lhi = lane >> 4;

    f32x4 acc[4][4];
#pragma unroll
    for (int m = 0; m < 4; m++)
#pragma unroll
        for (int n = 0; n < 4; n++)
            acc[m][n] = (f32x4){0.f, 0.f, 0.f, 0.f};

    for (int k0 = 0; k0 < K; k0 += BK) {
#pragma unroll
        for (int q = 0; q < 4; q++) {
            int chunk = q * 256 + t;
            int row = chunk >> 3;
            int il = (chunk & 7) ^ (row & 7);
            ASYNC16(A  + (long)(row0 + row) * K + k0 + il * 8, (char*)As + chunk * 16);
            ASYNC16(Wt + (long)(col0 + row) * K + k0 + il * 8, (char*)Bs + chunk * 16);
        }
        __syncthreads();
#pragma unroll
        for (int kk = 0; kk < 2; kk++) {
            bf16x8 af[4], bfr[4];
#pragma unroll
            for (int m = 0; m < 4; m++) {
                int rl = wr * 64 + m * 16 + l16;
                int off = rl * 128 + ((kk * 64 + lhi * 16) ^ ((rl & 7) << 4));
                af[m] = *(const bf16x8*)((const char*)As + off);
            }
#pragma unroll
            for (int n = 0; n < 4; n++) {
                int rl = wc * 64 + n * 16 + l16;
                int off = rl * 128 + ((kk * 64 + lhi * 16) ^ ((rl & 7) << 4));
                bfr[n] = *(const bf16x8*)((const char*)Bs + off);
            }
#pragma unroll
            for (int m = 0; m < 4; m++)
#pragma unroll
                for (int n = 0; n < 4; n++)
                    acc[m][n] = __builtin_amdgcn_mfma_f32_16x16x32_bf16(bfr[n], af[m], acc[m][n], 0, 0, 0);
        }
        __syncthreads();
    }

    // coalesced epilogue: 4 consecutive cols per fragment
    float4 bvn[4];
#pragma unroll
    for (int n = 0; n < 4; n++) {
        int colb = col0 + wc * 64 + n * 16 + lhi * 4;
        bvn[n] = (colb < DHID) ? *(const float4*)&bl[colb]
                               : *(const float4*)&br[colb - DHID];
    }
#pragma unroll
    for (int m = 0; m < 4; m++) {
        int row = row0 + wr * 64 + m * 16 + l16;
        if (row < NN) {
#pragma unroll
            for (int n = 0; n < 4; n++) {
                int colb = col0 + wc * 64 + n * 16 + lhi * 4;
                ushort4 p;
                p.x = f2bf(acc[m][n][0] + bvn[n].x);
                p.y = f2bf(acc[m][n][1] + bvn[n].y);
                p.z = f2bf(acc[m][n][2] + bvn[n].z);
                p.w = f2bf(acc[m][n][3] + bvn[n].w);
                *(ushort4*)&out[(long)row * NLR + colb] = p;
            }
        }
    }
}

// ---------------- fused per-node logits + softmax + aggregate (+log_softmax) ----------------
// One WAVE per dst node (4 nodes / 256-thr block). Lane owns channels lane*8..+7;
// head = lane>>3 (3-shfl reduce). Exact r2 core: guarded 1-deep prefetch,
// fmax leaky, always-rescale online max, exp2 domain.
// MODE 0: +bias, ELU, write bf16 (h1). MODE 1: +bias, write f32 h2 + fused log_softmax.

#define CVT8(u, f)                                  \
    f[0] = __uint_as_float((u).x << 16);            \
    f[1] = __uint_as_float((u).x & 0xffff0000u);    \
    f[2] = __uint_as_float((u).y << 16);            \
    f[3] = __uint_as_float((u).y & 0xffff0000u);    \
    f[4] = __uint_as_float((u).z << 16);            \
    f[5] = __uint_as_float((u).z & 0xffff0000u);    \
    f[6] = __uint_as_float((u).w << 16);            \
    f[7] = __uint_as_float((u).w & 0xffff0000u);

template <int MODE>
__global__ __launch_bounds__(256) void aggregate_kernel(const ushort* __restrict__ lr,
                                                        const float* __restrict__ att,
                                                        const float* __restrict__ bias,
                                                        const int* __restrict__ csr_src,
                                                        const int* __restrict__ offs,
                                                        ushort* __restrict__ out_bf,
                                                        float* __restrict__ out_f32,
                                                        float* __restrict__ out_lsm) {
    int i = blockIdx.x * 4 + (threadIdx.x >> 6);
    int lane = threadIdx.x & 63;
    int c0 = lane << 3;

    uint4 ur = *(const uint4*)(lr + (long)i * NLR + DHID + c0);
    float rv[8];
    CVT8(ur, rv);
    float av[8];
    *(float4*)&av[0] = *(const float4*)&att[c0];
    *(float4*)&av[4] = *(const float4*)&att[c0 + 4];

    int beg = offs[i], end = offs[i + 1];
    float m = -3.0e38f, d = 0.f;
    float acc[8] = {0.f, 0.f, 0.f, 0.f, 0.f, 0.f, 0.f, 0.f};

    int j = csr_src[beg];
    uint4 v = *(const uint4*)(lr + (long)j * NLR + c0);

    for (int k = beg; k < end; k++) {
        uint4 vc = v;
        int kn = (k + 1 < end) ? k + 1 : k;
        int jn = csr_src[kn];
        v = *(const uint4*)(lr + (long)jn * NLR + c0);

        float lx[8];
        CVT8(vc, lx);
        float s = 0.f;
#pragma unroll
        for (int c = 0; c < 8; c++) {
            float e = lx[c] + rv[c];
            e = fmaxf(e, 0.2f * e);          // leaky_relu, branchless
            s = fmaf(av[c], e, s);
        }
        s *= 1.44269504f;                    // exp2 domain
        s += __shfl_xor(s, 1);
        s += __shfl_xor(s, 2);
        s += __shfl_xor(s, 4);

        if (s > m) {
            float sc = exp2f(m - s);
            d *= sc;
#pragma unroll
            for (int c = 0; c < 8; c++) acc[c] *= sc;
            m = s;
        }
        float wgt = exp2f(s - m);
        d += wgt;
#pragma unroll
        for (int c = 0; c < 8; c++) acc[c] = fmaf(wgt, lx[c], acc[c]);
    }

    float inv = 1.f / d;
    float o[8];
    float4 bi0 = *(const float4*)&bias[c0];
    float4 bi1 = *(const float4*)&bias[c0 + 4];
    o[0] = fmaf(acc[0], inv, bi0.x); o[1] = fmaf(acc[1], inv, bi0.y);
    o[2] = fmaf(acc[2], inv, bi0.z); o[3] = fmaf(acc[3], inv, bi0.w);
    o[4] = fmaf(acc[4], inv, bi1.x); o[5] = fmaf(acc[5], inv, bi1.y);
    o[6] = fmaf(acc[6], inv, bi1.z); o[7] = fmaf(acc[7], inv, bi1.w);

    if (MODE == 0) {
#pragma unroll
        for (int c = 0; c < 8; c++) o[c] = (o[c] > 0.f) ? o[c] : expm1f(o[c]);
        uint4 p;
        p.x = (uint)f2bf(o[0]) | ((uint)f2bf(o[1]) << 16);
        p.y = (uint)f2bf(o[2]) | ((uint)f2bf(o[3]) << 16);
        p.z = (uint)f2bf(o[4]) | ((uint)f2bf(o[5]) << 16);
        p.w = (uint)f2bf(o[6]) | ((uint)f2bf(o[7]) << 16);
        *(uint4*)(out_bf + (long)i * DHID + c0) = p;
    } else {
        *(float4*)&out_f32[(long)i * DHID + c0]     = *(float4*)&o[0];
        *(float4*)&out_f32[(long)i * DHID + c0 + 4] = *(float4*)&o[4];
        // fused log_softmax over the 512-wide row held by this wave
        float mx = o[0];
#pragma unroll
        for (int c = 1; c < 8; c++) mx = fmaxf(mx, o[c]);
#pragma unroll
        for (int off = 1; off < 64; off <<= 1) mx = fmaxf(mx, __shfl_xor(mx, off));
        float se = 0.f;
#pragma unroll
        for (int c = 0; c < 8; c++) se += __expf(o[c] - mx);
#pragma unroll
        for (int off = 1; off < 64; off <<= 1) se += __shfl_xor(se, off);
        float lg = mx + logf(se);
        float l0[8];
#pragma unroll
        for (int c = 0; c < 8; c++) l0[c] = o[c] - lg;
        *(float4*)&out_lsm[(long)i * DHID + c0]     = *(float4*)&l0[0];
        *(float4*)&out_lsm[(long)i * DHID + c0 + 4] = *(float4*)&l0[4];
    }
}

// ---------------- launch ----------------

extern "C" void kernel_launch(void* const* d_in, const int* in_sizes, int n_in,
                              void* d_out, int out_size, void* d_ws, size_t ws_size,
                              hipStream_t stream) {
    const float* x     = (const float*)d_in[0];
    const int*   ei    = (const int*)d_in[1];
    const float* Wl1   = (const float*)d_in[2];
    const float* bl1   = (const float*)d_in[3];
    const float* Wr1   = (const float*)d_in[4];
    const float* br1   = (const float*)d_in[5];
    const float* att1  = (const float*)d_in[6];
    const float* bias1 = (const float*)d_in[7];
    const float* Wl2   = (const float*)d_in[8];
    const float* bl2   = (const float*)d_in[9];
    const float* Wr2   = (const float*)d_in[10];
    const float* br2   = (const float*)d_in[11];
    const float* att2  = (const float*)d_in[12];
    const float* bias2 = (const float*)d_in[13];

    float* out = (float*)d_out;
    float* h2  = out;                      // final layer-2 output [NN,512] f32
    float* lsm = out + (long)NN * DHID;    // log_softmax area

    ushort* lrbuf  = (ushort*)d_ws;                      // [NN,1024] bf16
    ushort* Abf    = lrbuf + (long)NN * NLR;             // [MPAD,512] bf16
    ushort* Wt1    = Abf + (long)MPAD * DHID;            // [1024,256] bf16
    ushort* Wt2    = Wt1 + (long)NLR * D_IN;             // [1024,512] bf16
    int*    csr_src = (int*)(Wt2 + (long)NLR * DHID);    // ET + CPAD
    int*    count   = csr_src + ET + CPAD;               // NN
    int*    offs    = count + NN;                        // NN+1
    int*    cursor  = offs + NN + 1;                     // NN

    const int* srcv = ei;
    const int* dstv = ei + NE;

    prep_a<<<(int)((N1Q + N2Q + 255) / 256), 256, 0, stream>>>(x, Abf);
    transpose_w2<<<dim3(DHID / 32, NLR / 32, 2), 256, 0, stream>>>(Wl1, Wr1, Wt1,
                                                                   Wl2, Wr2, Wt2);

    init_count<<<(NN + 255) / 256, 256, 0, stream>>>(count, csr_src);
    hist_kernel<<<(NE + 255) / 256, 256, 0, stream>>>(dstv, count);
    scan_kernel<<<1, 1024, 0, stream>>>(count, offs, cursor);
    scatter_kernel<<<(ET + 255) / 256, 256, 0, stream>>>(srcv, dstv, cursor, csr_src);

    dim3 ggrid((NN + BM - 1) / BM, NLR / BN);

    // layer 1
    gemm_mfma<<<ggrid, 256, 0, stream>>>(Abf, D_IN, Wt1, bl1, br1, lrbuf);
    aggregate_kernel<0><<<NN / 4, 256, 0, stream>>>(lrbuf, att1, bias1, csr_src, offs, Abf, nullptr, nullptr);

    // layer 2 (log_softmax fused into the aggregate epilogue)
    gemm_mfma<<<ggrid, 256, 0, stream>>>(Abf, DHID, Wt2, bl2, br2, lrbuf);
    aggregate_kernel<1><<<NN / 4, 256, 0, stream>>>(lrbuf, att2, bias2, csr_src, offs, nullptr, h2, lsm);
}

// Round 9
// 262.562 us; speedup vs baseline: 1.0255x; 1.0255x over previous
//
#include <hip/hip_runtime.h>
#include <math.h>

#define NN   20000
#define NE   320000
#define ET   (NE + NN)
#define CPAD 16
#define D_IN 256
#define DHID 512    // H * DH = H * DOUT
#define NLR  1024   // combined l|r width
#define MPAD 20096  // 157 * 128
#define NROWP 157   // MPAD / 128
#define NCOLP 8     // NLR / 128

typedef __attribute__((ext_vector_type(8))) short bf16x8;
typedef __attribute__((ext_vector_type(4))) float f32x4;

typedef __attribute__((address_space(3))) uint       lds_uint;
typedef __attribute__((address_space(1))) const uint gbl_uint;
#define ASYNC16(gp, lp) \
    __builtin_amdgcn_global_load_lds((gbl_uint*)(gp), (lds_uint*)(lp), 16, 0, 0)

__device__ __forceinline__ ushort f2bf(float f) {
    uint u = __float_as_uint(f);
    return (ushort)((u + 0x7fffu + ((u >> 16) & 1u)) >> 16);
}

// ---------------- CSR build ----------------

__global__ __launch_bounds__(256) void init_count(int* count, int* csr_src) {
    int i = blockIdx.x * 256 + threadIdx.x;
    if (i < NN) count[i] = 1;  // self-loop
    if (i < CPAD) csr_src[ET + i] = 0;
}

__global__ __launch_bounds__(256) void hist_kernel(const int* __restrict__ dstv,
                                                   int* __restrict__ count) {
    int e = blockIdx.x * 256 + threadIdx.x;
    if (e < NE) atomicAdd(&count[dstv[e]], 1);
}

__global__ __launch_bounds__(1024) void scan_kernel(const int* __restrict__ count,
                                                    int* __restrict__ offs,
                                                    int* __restrict__ cursor) {
    __shared__ int sm[1024];
    const int CH = 20;
    int t = threadIdx.x;
    int base = t * CH;
    int local[CH];
    int s = 0;
#pragma unroll
    for (int i = 0; i < CH; i++) {
        int idx = base + i;
        int v = (idx < NN) ? count[idx] : 0;
        local[i] = s;
        s += v;
    }
    sm[t] = s;
    __syncthreads();
    for (int o = 1; o < 1024; o <<= 1) {
        int v = (t >= o) ? sm[t - o] : 0;
        __syncthreads();
        sm[t] += v;
        __syncthreads();
    }
    int pref = (t > 0) ? sm[t - 1] : 0;
#pragma unroll
    for (int i = 0; i < CH; i++) {
        int idx = base + i;
        if (idx < NN) {
            int o_ = pref + local[i];
            offs[idx] = o_;
            cursor[idx] = o_;
        }
    }
    if (t == 1023) offs[NN] = sm[1023];
}

__global__ __launch_bounds__(256) void scatter_kernel(const int* __restrict__ srcv,
                                                      const int* __restrict__ dstv,
                                                      int* __restrict__ cursor,
                                                      int* __restrict__ csr_src) {
    int e = blockIdx.x * 256 + threadIdx.x;
    if (e >= ET) return;
    int s, d;
    if (e < NE) { s = srcv[e]; d = dstv[e]; }
    else        { s = e - NE;  d = s; }
    int pos = atomicAdd(&cursor[d], 1);
    csr_src[pos] = s;
}

// ---------------- merged pre-pass: x->bf16 [MPAD,256] + zero pad of [MPAD,512] view ----------------

#define N1Q ((long)MPAD * D_IN / 4)
#define N2Q ((long)(MPAD - NN) * DHID / 4)

__global__ __launch_bounds__(256) void prep_a(const float* __restrict__ x,
                                              ushort* __restrict__ a) {
    long t = (long)blockIdx.x * 256 + threadIdx.x;
    if (t < N1Q) {
        long e = t * 4;
        int row = (int)(e >> 8);
        float4 v = make_float4(0.f, 0.f, 0.f, 0.f);
        if (row < NN) v = *(const float4*)&x[e];
        ushort4 o;
        o.x = f2bf(v.x); o.y = f2bf(v.y); o.z = f2bf(v.z); o.w = f2bf(v.w);
        *(ushort4*)&a[e] = o;
    } else if (t < N1Q + N2Q) {
        long e = (t - N1Q) * 4 + (long)NN * DHID;
        ushort4 z = {0, 0, 0, 0};
        *(ushort4*)&a[e] = z;
    }
}

// ---------------- merged weight transpose: both layers via blockIdx.z ----------------

__global__ __launch_bounds__(256) void transpose_w2(const float* __restrict__ Wl1,
                                                    const float* __restrict__ Wr1,
                                                    ushort* __restrict__ Wt1,
                                                    const float* __restrict__ Wl2,
                                                    const float* __restrict__ Wr2,
                                                    ushort* __restrict__ Wt2) {
    __shared__ float tile[32][33];
    int z = blockIdx.z;
    int K = z ? DHID : D_IN;
    int k0 = blockIdx.x * 32;
    if (k0 >= K) return;
    int n0 = blockIdx.y * 32;
    int tx = threadIdx.x & 31, ty = threadIdx.x >> 5;
    const float* __restrict__ W = (n0 < DHID) ? (z ? Wl2 : Wl1) : (z ? Wr2 : Wr1);
    ushort* __restrict__ Wt = z ? Wt2 : Wt1;
    int nb = (n0 < DHID) ? n0 : n0 - DHID;
#pragma unroll
    for (int r = ty; r < 32; r += 8)
        tile[r][tx] = W[(long)(k0 + r) * DHID + nb + tx];
    __syncthreads();
#pragma unroll
    for (int r = ty; r < 32; r += 8)
        Wt[(long)(n0 + r) * K + k0 + tx] = f2bf(tile[tx][r]);
}

// ---------------- bf16 MFMA GEMM: out[M,1024] = A[M,K] @ Wt^T + (bl|br) ----------------
// 1D grid 1256 blocks, bijective XCD-chunk swizzle: each XCD owns a contiguous
// ~20-row-panel chunk and iterates its 8 col-blocks consecutively, so each
// A-panel (128 x K) is fetched into ONE XCD's L2 once and reused 8x.
// (2D x-fastest grid made every XCD walk ALL row panels: 8x full-A L2 fill.)
// Operand-swapped mfma(bfr, af) -> C^T fragments: 4 consecutive cols/lane
// -> ushort4 stores.

#define BM 128
#define BN 128
#define BK 64

__global__ __launch_bounds__(256) void gemm_mfma(const ushort* __restrict__ A, int K,
                                                 const ushort* __restrict__ Wt,
                                                 const float* __restrict__ bl,
                                                 const float* __restrict__ br,
                                                 ushort* __restrict__ out) {
    __shared__ ushort As[BM * BK];
    __shared__ ushort Bs[BN * BK];

    int t = threadIdx.x;
    int bid = blockIdx.x;
    int xcd = bid & 7;
    int idx = bid >> 3;
    int gl = xcd * NROWP + idx;     // bijective: [0, 1256)
    int row0 = (gl >> 3) * BM;      // row-panel: shared by 8 consecutive gl
    int col0 = (gl & 7) * BN;

    int lane = t & 63, w = t >> 6;
    int wr = w >> 1, wc = w & 1;
    int l16 = lane & 15, lhi = lane >> 4;

    f32x4 acc[4][4];
#pragma unroll
    for (int m = 0; m < 4; m++)
#pragma unroll
        for (int n = 0; n < 4; n++)
            acc[m][n] = (f32x4){0.f, 0.f, 0.f, 0.f};

    for (int k0 = 0; k0 < K; k0 += BK) {
#pragma unroll
        for (int q = 0; q < 4; q++) {
            int chunk = q * 256 + t;
            int row = chunk >> 3;
            int il = (chunk & 7) ^ (row & 7);
            ASYNC16(A  + (long)(row0 + row) * K + k0 + il * 8, (char*)As + chunk * 16);
            ASYNC16(Wt + (long)(col0 + row) * K + k0 + il * 8, (char*)Bs + chunk * 16);
        }
        __syncthreads();
#pragma unroll
        for (int kk = 0; kk < 2; kk++) {
            bf16x8 af[4], bfr[4];
#pragma unroll
            for (int m = 0; m < 4; m++) {
                int rl = wr * 64 + m * 16 + l16;
                int off = rl * 128 + ((kk * 64 + lhi * 16) ^ ((rl & 7) << 4));
                af[m] = *(const bf16x8*)((const char*)As + off);
            }
#pragma unroll
            for (int n = 0; n < 4; n++) {
                int rl = wc * 64 + n * 16 + l16;
                int off = rl * 128 + ((kk * 64 + lhi * 16) ^ ((rl & 7) << 4));
                bfr[n] = *(const bf16x8*)((const char*)Bs + off);
            }
#pragma unroll
            for (int m = 0; m < 4; m++)
#pragma unroll
                for (int n = 0; n < 4; n++)
                    acc[m][n] = __builtin_amdgcn_mfma_f32_16x16x32_bf16(bfr[n], af[m], acc[m][n], 0, 0, 0);
        }
        __syncthreads();
    }

    // coalesced epilogue: 4 consecutive cols per fragment
    float4 bvn[4];
#pragma unroll
    for (int n = 0; n < 4; n++) {
        int colb = col0 + wc * 64 + n * 16 + lhi * 4;
        bvn[n] = (colb < DHID) ? *(const float4*)&bl[colb]
                               : *(const float4*)&br[colb - DHID];
    }
#pragma unroll
    for (int m = 0; m < 4; m++) {
        int row = row0 + wr * 64 + m * 16 + l16;
        if (row < NN) {
#pragma unroll
            for (int n = 0; n < 4; n++) {
                int colb = col0 + wc * 64 + n * 16 + lhi * 4;
                ushort4 p;
                p.x = f2bf(acc[m][n][0] + bvn[n].x);
                p.y = f2bf(acc[m][n][1] + bvn[n].y);
                p.z = f2bf(acc[m][n][2] + bvn[n].z);
                p.w = f2bf(acc[m][n][3] + bvn[n].w);
                *(ushort4*)&out[(long)row * NLR + colb] = p;
            }
        }
    }
}

// ---------------- fused per-node logits + softmax + aggregate (+log_softmax) ----------------
// One WAVE per dst node (4 nodes / 256-thr block). Lane owns channels lane*8..+7;
// head = lane>>3 (3-shfl reduce). Guarded 1-deep prefetch, fmax leaky,
// always-rescale online max, exp2 domain.
// MODE 0: +bias, ELU, write bf16 (h1). MODE 1: +bias, write f32 h2 + fused log_softmax.

#define CVT8(u, f)                                  \
    f[0] = __uint_as_float((u).x << 16);            \
    f[1] = __uint_as_float((u).x & 0xffff0000u);    \
    f[2] = __uint_as_float((u).y << 16);            \
    f[3] = __uint_as_float((u).y & 0xffff0000u);    \
    f[4] = __uint_as_float((u).z << 16);            \
    f[5] = __uint_as_float((u).z & 0xffff0000u);    \
    f[6] = __uint_as_float((u).w << 16);            \
    f[7] = __uint_as_float((u).w & 0xffff0000u);

template <int MODE>
__global__ __launch_bounds__(256) void aggregate_kernel(const ushort* __restrict__ lr,
                                                        const float* __restrict__ att,
                                                        const float* __restrict__ bias,
                                                        const int* __restrict__ csr_src,
                                                        const int* __restrict__ offs,
                                                        ushort* __restrict__ out_bf,
                                                        float* __restrict__ out_f32,
                                                        float* __restrict__ out_lsm) {
    int i = blockIdx.x * 4 + (threadIdx.x >> 6);
    int lane = threadIdx.x & 63;
    int c0 = lane << 3;

    uint4 ur = *(const uint4*)(lr + (long)i * NLR + DHID + c0);
    float rv[8];
    CVT8(ur, rv);
    float av[8];
    *(float4*)&av[0] = *(const float4*)&att[c0];
    *(float4*)&av[4] = *(const float4*)&att[c0 + 4];

    int beg = offs[i], end = offs[i + 1];
    float m = -3.0e38f, d = 0.f;
    float acc[8] = {0.f, 0.f, 0.f, 0.f, 0.f, 0.f, 0.f, 0.f};

    int j = csr_src[beg];
    uint4 v = *(const uint4*)(lr + (long)j * NLR + c0);

    for (int k = beg; k < end; k++) {
        uint4 vc = v;
        int kn = (k + 1 < end) ? k + 1 : k;
        int jn = csr_src[kn];
        v = *(const uint4*)(lr + (long)jn * NLR + c0);

        float lx[8];
        CVT8(vc, lx);
        float s = 0.f;
#pragma unroll
        for (int c = 0; c < 8; c++) {
            float e = lx[c] + rv[c];
            e = fmaxf(e, 0.2f * e);          // leaky_relu, branchless
            s = fmaf(av[c], e, s);
        }
        s *= 1.44269504f;                    // exp2 domain
        s += __shfl_xor(s, 1);
        s += __shfl_xor(s, 2);
        s += __shfl_xor(s, 4);

        if (s > m) {
            float sc = exp2f(m - s);
            d *= sc;
#pragma unroll
            for (int c = 0; c < 8; c++) acc[c] *= sc;
            m = s;
        }
        float wgt = exp2f(s - m);
        d += wgt;
#pragma unroll
        for (int c = 0; c < 8; c++) acc[c] = fmaf(wgt, lx[c], acc[c]);
    }

    float inv = 1.f / d;
    float o[8];
    float4 bi0 = *(const float4*)&bias[c0];
    float4 bi1 = *(const float4*)&bias[c0 + 4];
    o[0] = fmaf(acc[0], inv, bi0.x); o[1] = fmaf(acc[1], inv, bi0.y);
    o[2] = fmaf(acc[2], inv, bi0.z); o[3] = fmaf(acc[3], inv, bi0.w);
    o[4] = fmaf(acc[4], inv, bi1.x); o[5] = fmaf(acc[5], inv, bi1.y);
    o[6] = fmaf(acc[6], inv, bi1.z); o[7] = fmaf(acc[7], inv, bi1.w);

    if (MODE == 0) {
#pragma unroll
        for (int c = 0; c < 8; c++) o[c] = (o[c] > 0.f) ? o[c] : expm1f(o[c]);
        uint4 p;
        p.x = (uint)f2bf(o[0]) | ((uint)f2bf(o[1]) << 16);
        p.y = (uint)f2bf(o[2]) | ((uint)f2bf(o[3]) << 16);
        p.z = (uint)f2bf(o[4]) | ((uint)f2bf(o[5]) << 16);
        p.w = (uint)f2bf(o[6]) | ((uint)f2bf(o[7]) << 16);
        *(uint4*)(out_bf + (long)i * DHID + c0) = p;
    } else {
        *(float4*)&out_f32[(long)i * DHID + c0]     = *(float4*)&o[0];
        *(float4*)&out_f32[(long)i * DHID + c0 + 4] = *(float4*)&o[4];
        // fused log_softmax over the 512-wide row held by this wave
        float mx = o[0];
#pragma unroll
        for (int c = 1; c < 8; c++) mx = fmaxf(mx, o[c]);
#pragma unroll
        for (int off = 1; off < 64; off <<= 1) mx = fmaxf(mx, __shfl_xor(mx, off));
        float se = 0.f;
#pragma unroll
        for (int c = 0; c < 8; c++) se += __expf(o[c] - mx);
#pragma unroll
        for (int off = 1; off < 64; off <<= 1) se += __shfl_xor(se, off);
        float lg = mx + logf(se);
        float l0[8];
#pragma unroll
        for (int c = 0; c < 8; c++) l0[c] = o[c] - lg;
        *(float4*)&out_lsm[(long)i * DHID + c0]     = *(float4*)&l0[0];
        *(float4*)&out_lsm[(long)i * DHID + c0 + 4] = *(float4*)&l0[4];
    }
}

// ---------------- launch ----------------

extern "C" void kernel_launch(void* const* d_in, const int* in_sizes, int n_in,
                              void* d_out, int out_size, void* d_ws, size_t ws_size,
                              hipStream_t stream) {
    const float* x     = (const float*)d_in[0];
    const int*   ei    = (const int*)d_in[1];
    const float* Wl1   = (const float*)d_in[2];
    const float* bl1   = (const float*)d_in[3];
    const float* Wr1   = (const float*)d_in[4];
    const float* br1   = (const float*)d_in[5];
    const float* att1  = (const float*)d_in[6];
    const float* bias1 = (const float*)d_in[7];
    const float* Wl2   = (const float*)d_in[8];
    const float* bl2   = (const float*)d_in[9];
    const float* Wr2   = (const float*)d_in[10];
    const float* br2   = (const float*)d_in[11];
    const float* att2  = (const float*)d_in[12];
    const float* bias2 = (const float*)d_in[13];

    float* out = (float*)d_out;
    float* h2  = out;                      // final layer-2 output [NN,512] f32
    float* lsm = out + (long)NN * DHID;    // log_softmax area

    ushort* lrbuf  = (ushort*)d_ws;                      // [NN,1024] bf16
    ushort* Abf    = lrbuf + (long)NN * NLR;             // [MPAD,512] bf16
    ushort* Wt1    = Abf + (long)MPAD * DHID;            // [1024,256] bf16
    ushort* Wt2    = Wt1 + (long)NLR * D_IN;             // [1024,512] bf16
    int*    csr_src = (int*)(Wt2 + (long)NLR * DHID);    // ET + CPAD
    int*    count   = csr_src + ET + CPAD;               // NN
    int*    offs    = count + NN;                        // NN+1
    int*    cursor  = offs + NN + 1;                     // NN

    const int* srcv = ei;
    const int* dstv = ei + NE;

    prep_a<<<(int)((N1Q + N2Q + 255) / 256), 256, 0, stream>>>(x, Abf);
    transpose_w2<<<dim3(DHID / 32, NLR / 32, 2), 256, 0, stream>>>(Wl1, Wr1, Wt1,
                                                                   Wl2, Wr2, Wt2);

    init_count<<<(NN + 255) / 256, 256, 0, stream>>>(count, csr_src);
    hist_kernel<<<(NE + 255) / 256, 256, 0, stream>>>(dstv, count);
    scan_kernel<<<1, 1024, 0, stream>>>(count, offs, cursor);
    scatter_kernel<<<(ET + 255) / 256, 256, 0, stream>>>(srcv, dstv, cursor, csr_src);

    // layer 1
    gemm_mfma<<<NROWP * NCOLP, 256, 0, stream>>>(Abf, D_IN, Wt1, bl1, br1, lrbuf);
    aggregate_kernel<0><<<NN / 4, 256, 0, stream>>>(lrbuf, att1, bias1, csr_src, offs, Abf, nullptr, nullptr);

    // layer 2 (log_softmax fused into the aggregate epilogue)
    gemm_mfma<<<NROWP * NCOLP, 256, 0, stream>>>(Abf, DHID, Wt2, bl2, br2, lrbuf);
    aggregate_kernel<1><<<NN / 4, 256, 0, stream>>>(lrbuf, att2, bias2, csr_src, offs, nullptr, h2, lsm);
}

// Round 10
// 254.677 us; speedup vs baseline: 1.0573x; 1.0310x over previous
//
#include <hip/hip_runtime.h>
#include <math.h>

#define NN   20000
#define NE   320000
#define ET   (NE + NN)
#define CPAD 16
#define D_IN 256
#define DHID 512    // H * DH = H * DOUT
#define NLR  1024   // combined l|r width
#define MPAD 20096  // 157 * 128
#define NROWP 157   // MPAD / 128
#define NCOLP 8     // NLR / 128

typedef __attribute__((ext_vector_type(8))) short bf16x8;
typedef __attribute__((ext_vector_type(4))) float f32x4;

typedef __attribute__((address_space(3))) uint       lds_uint;
typedef __attribute__((address_space(1))) const uint gbl_uint;
#define ASYNC16(gp, lp) \
    __builtin_amdgcn_global_load_lds((gbl_uint*)(gp), (lds_uint*)(lp), 16, 0, 0)

__device__ __forceinline__ ushort f2bf(float f) {
    uint u = __float_as_uint(f);
    return (ushort)((u + 0x7fffu + ((u >> 16) & 1u)) >> 16);
}

// ---------------- K1: prep_a (x->bf16 + pad zero)  ||  init_count + csr pad ----------------

#define N1Q ((long)MPAD * D_IN / 4)
#define N2Q ((long)(MPAD - NN) * DHID / 4)
#define PREP_BLKS ((int)((N1Q + N2Q + 255) / 256))   // 5072
#define INIT_BLKS ((NN + 255) / 256)                 // 79

__global__ __launch_bounds__(256) void k_prep(const float* __restrict__ x,
                                              ushort* __restrict__ a,
                                              int* __restrict__ count,
                                              int* __restrict__ csr_src) {
    int b = blockIdx.x;
    if (b < PREP_BLKS) {
        long t = (long)b * 256 + threadIdx.x;
        if (t < N1Q) {
            long e = t * 4;
            int row = (int)(e >> 8);
            float4 v = make_float4(0.f, 0.f, 0.f, 0.f);
            if (row < NN) v = *(const float4*)&x[e];
            ushort4 o;
            o.x = f2bf(v.x); o.y = f2bf(v.y); o.z = f2bf(v.z); o.w = f2bf(v.w);
            *(ushort4*)&a[e] = o;
        } else if (t < N1Q + N2Q) {
            long e = (t - N1Q) * 4 + (long)NN * DHID;
            ushort4 z = {0, 0, 0, 0};
            *(ushort4*)&a[e] = z;
        }
    } else {
        int i = (b - PREP_BLKS) * 256 + threadIdx.x;
        if (i < NN) count[i] = 1;        // self-loop
        if (i < CPAD) csr_src[ET + i] = 0;
    }
}

// ---------------- K2: hist (needs count init)  ||  weight transposes ----------------

#define HIST_BLKS ((NE + 255) / 256)                 // 1250
#define TW_BLKS   1024                               // 16 x 32 x 2

__global__ __launch_bounds__(256) void k_hist_tw(const int* __restrict__ dstv,
                                                 int* __restrict__ count,
                                                 const float* __restrict__ Wl1,
                                                 const float* __restrict__ Wr1,
                                                 ushort* __restrict__ Wt1,
                                                 const float* __restrict__ Wl2,
                                                 const float* __restrict__ Wr2,
                                                 ushort* __restrict__ Wt2) {
    __shared__ float tile[32][33];
    int b = blockIdx.x;
    if (b < HIST_BLKS) {
        int e = b * 256 + threadIdx.x;
        if (e < NE) atomicAdd(&count[dstv[e]], 1);
        return;
    }
    int idx = b - HIST_BLKS;         // [0, 1024)
    int z = idx >> 9;
    int rem = idx & 511;
    int K = z ? DHID : D_IN;
    int k0 = (rem & 15) * 32;
    if (k0 >= K) return;             // uniform per block
    int n0 = (rem >> 4) * 32;
    int tx = threadIdx.x & 31, ty = threadIdx.x >> 5;
    const float* __restrict__ W = (n0 < DHID) ? (z ? Wl2 : Wl1) : (z ? Wr2 : Wr1);
    ushort* __restrict__ Wt = z ? Wt2 : Wt1;
    int nb = (n0 < DHID) ? n0 : n0 - DHID;
#pragma unroll
    for (int r = ty; r < 32; r += 8)
        tile[r][tx] = W[(long)(k0 + r) * DHID + nb + tx];
    __syncthreads();
#pragma unroll
    for (int r = ty; r < 32; r += 8)
        Wt[(long)(n0 + r) * K + k0 + tx] = f2bf(tile[tx][r]);
}

// ---------------- K3: scan ----------------

__global__ __launch_bounds__(1024) void scan_kernel(const int* __restrict__ count,
                                                    int* __restrict__ offs,
                                                    int* __restrict__ cursor) {
    __shared__ int sm[1024];
    const int CH = 20;
    int t = threadIdx.x;
    int base = t * CH;
    int local[CH];
    int s = 0;
#pragma unroll
    for (int i = 0; i < CH; i++) {
        int idx = base + i;
        int v = (idx < NN) ? count[idx] : 0;
        local[i] = s;
        s += v;
    }
    sm[t] = s;
    __syncthreads();
    for (int o = 1; o < 1024; o <<= 1) {
        int v = (t >= o) ? sm[t - o] : 0;
        __syncthreads();
        sm[t] += v;
        __syncthreads();
    }
    int pref = (t > 0) ? sm[t - 1] : 0;
#pragma unroll
    for (int i = 0; i < CH; i++) {
        int idx = base + i;
        if (idx < NN) {
            int o_ = pref + local[i];
            offs[idx] = o_;
            cursor[idx] = o_;
        }
    }
    if (t == 1023) offs[NN] = sm[1023];
}

// ---------------- K4/K6: bf16 MFMA GEMM  ||  (layer 1 only) scatter ----------------
// gemm blocks [0, 1256): 1D bijective XCD-chunk swizzle -- each XCD owns a
// contiguous ~20-row-panel chunk, iterating its 8 col-blocks consecutively
// (A-panel fetched into ONE XCD L2, reused 8x). Operand-swapped mfma -> C^T
// fragments -> 4 consecutive cols/lane -> ushort4 stores.
// blocks >= 1256 (layer-1 launch only): CSR scatter, hides under the gemm.

#define BM 128
#define BN 128
#define BK 64
#define GEMM_BLKS (NROWP * NCOLP)                    // 1256
#define SCAT_BLKS ((ET + 255) / 256)                 // 1329

__global__ __launch_bounds__(256) void k_gemm_scatter(const ushort* __restrict__ A, int K,
                                                      const ushort* __restrict__ Wt,
                                                      const float* __restrict__ bl,
                                                      const float* __restrict__ br,
                                                      ushort* __restrict__ out,
                                                      const int* __restrict__ srcv,
                                                      const int* __restrict__ dstv,
                                                      int* __restrict__ cursor,
                                                      int* __restrict__ csr_src) {
    __shared__ ushort As[BM * BK];
    __shared__ ushort Bs[BN * BK];

    int bid = blockIdx.x;
    if (bid >= GEMM_BLKS) {          // scatter path (layer-1 launch only)
        int e = (bid - GEMM_BLKS) * 256 + threadIdx.x;
        if (e >= ET) return;
        int s, d;
        if (e < NE) { s = srcv[e]; d = dstv[e]; }
        else        { s = e - NE;  d = s; }
        int pos = atomicAdd(&cursor[d], 1);
        csr_src[pos] = s;
        return;
    }

    int t = threadIdx.x;
    int xcd = bid & 7;
    int idx = bid >> 3;
    int gl = xcd * NROWP + idx;      // bijective: [0, 1256)
    int row0 = (gl >> 3) * BM;
    int col0 = (gl & 7) * BN;

    int lane = t & 63, w = t >> 6;
    int wr = w >> 1, wc = w & 1;
    int l16 = lane & 15, lhi = lane >> 4;

    f32x4 acc[4][4];
#pragma unroll
    for (int m = 0; m < 4; m++)
#pragma unroll
        for (int n = 0; n < 4; n++)
            acc[m][n] = (f32x4){0.f, 0.f, 0.f, 0.f};

    for (int k0 = 0; k0 < K; k0 += BK) {
#pragma unroll
        for (int q = 0; q < 4; q++) {
            int chunk = q * 256 + t;
            int row = chunk >> 3;
            int il = (chunk & 7) ^ (row & 7);
            ASYNC16(A  + (long)(row0 + row) * K + k0 + il * 8, (char*)As + chunk * 16);
            ASYNC16(Wt + (long)(col0 + row) * K + k0 + il * 8, (char*)Bs + chunk * 16);
        }
        __syncthreads();
#pragma unroll
        for (int kk = 0; kk < 2; kk++) {
            bf16x8 af[4], bfr[4];
#pragma unroll
            for (int m = 0; m < 4; m++) {
                int rl = wr * 64 + m * 16 + l16;
                int off = rl * 128 + ((kk * 64 + lhi * 16) ^ ((rl & 7) << 4));
                af[m] = *(const bf16x8*)((const char*)As + off);
            }
#pragma unroll
            for (int n = 0; n < 4; n++) {
                int rl = wc * 64 + n * 16 + l16;
                int off = rl * 128 + ((kk * 64 + lhi * 16) ^ ((rl & 7) << 4));
                bfr[n] = *(const bf16x8*)((const char*)Bs + off);
            }
#pragma unroll
            for (int m = 0; m < 4; m++)
#pragma unroll
                for (int n = 0; n < 4; n++)
                    acc[m][n] = __builtin_amdgcn_mfma_f32_16x16x32_bf16(bfr[n], af[m], acc[m][n], 0, 0, 0);
        }
        __syncthreads();
    }

    float4 bvn[4];
#pragma unroll
    for (int n = 0; n < 4; n++) {
        int colb = col0 + wc * 64 + n * 16 + lhi * 4;
        bvn[n] = (colb < DHID) ? *(const float4*)&bl[colb]
                               : *(const float4*)&br[colb - DHID];
    }
#pragma unroll
    for (int m = 0; m < 4; m++) {
        int row = row0 + wr * 64 + m * 16 + l16;
        if (row < NN) {
#pragma unroll
            for (int n = 0; n < 4; n++) {
                int colb = col0 + wc * 64 + n * 16 + lhi * 4;
                ushort4 p;
                p.x = f2bf(acc[m][n][0] + bvn[n].x);
                p.y = f2bf(acc[m][n][1] + bvn[n].y);
                p.z = f2bf(acc[m][n][2] + bvn[n].z);
                p.w = f2bf(acc[m][n][3] + bvn[n].w);
                *(ushort4*)&out[(long)row * NLR + colb] = p;
            }
        }
    }
}

// ---------------- fused per-node logits + softmax + aggregate (+log_softmax) ----------------

#define CVT8(u, f)                                  \
    f[0] = __uint_as_float((u).x << 16);            \
    f[1] = __uint_as_float((u).x & 0xffff0000u);    \
    f[2] = __uint_as_float((u).y << 16);            \
    f[3] = __uint_as_float((u).y & 0xffff0000u);    \
    f[4] = __uint_as_float((u).z << 16);            \
    f[5] = __uint_as_float((u).z & 0xffff0000u);    \
    f[6] = __uint_as_float((u).w << 16);            \
    f[7] = __uint_as_float((u).w & 0xffff0000u);

template <int MODE>
__global__ __launch_bounds__(256) void aggregate_kernel(const ushort* __restrict__ lr,
                                                        const float* __restrict__ att,
                                                        const float* __restrict__ bias,
                                                        const int* __restrict__ csr_src,
                                                        const int* __restrict__ offs,
                                                        ushort* __restrict__ out_bf,
                                                        float* __restrict__ out_f32,
                                                        float* __restrict__ out_lsm) {
    int i = blockIdx.x * 4 + (threadIdx.x >> 6);
    int lane = threadIdx.x & 63;
    int c0 = lane << 3;

    uint4 ur = *(const uint4*)(lr + (long)i * NLR + DHID + c0);
    float rv[8];
    CVT8(ur, rv);
    float av[8];
    *(float4*)&av[0] = *(const float4*)&att[c0];
    *(float4*)&av[4] = *(const float4*)&att[c0 + 4];

    int beg = offs[i], end = offs[i + 1];
    float m = -3.0e38f, d = 0.f;
    float acc[8] = {0.f, 0.f, 0.f, 0.f, 0.f, 0.f, 0.f, 0.f};

    int j = csr_src[beg];
    uint4 v = *(const uint4*)(lr + (long)j * NLR + c0);

    for (int k = beg; k < end; k++) {
        uint4 vc = v;
        int kn = (k + 1 < end) ? k + 1 : k;
        int jn = csr_src[kn];
        v = *(const uint4*)(lr + (long)jn * NLR + c0);

        float lx[8];
        CVT8(vc, lx);
        float s = 0.f;
#pragma unroll
        for (int c = 0; c < 8; c++) {
            float e = lx[c] + rv[c];
            e = fmaxf(e, 0.2f * e);          // leaky_relu, branchless
            s = fmaf(av[c], e, s);
        }
        s *= 1.44269504f;                    // exp2 domain
        s += __shfl_xor(s, 1);
        s += __shfl_xor(s, 2);
        s += __shfl_xor(s, 4);

        if (s > m) {
            float sc = exp2f(m - s);
            d *= sc;
#pragma unroll
            for (int c = 0; c < 8; c++) acc[c] *= sc;
            m = s;
        }
        float wgt = exp2f(s - m);
        d += wgt;
#pragma unroll
        for (int c = 0; c < 8; c++) acc[c] = fmaf(wgt, lx[c], acc[c]);
    }

    float inv = 1.f / d;
    float o[8];
    float4 bi0 = *(const float4*)&bias[c0];
    float4 bi1 = *(const float4*)&bias[c0 + 4];
    o[0] = fmaf(acc[0], inv, bi0.x); o[1] = fmaf(acc[1], inv, bi0.y);
    o[2] = fmaf(acc[2], inv, bi0.z); o[3] = fmaf(acc[3], inv, bi0.w);
    o[4] = fmaf(acc[4], inv, bi1.x); o[5] = fmaf(acc[5], inv, bi1.y);
    o[6] = fmaf(acc[6], inv, bi1.z); o[7] = fmaf(acc[7], inv, bi1.w);

    if (MODE == 0) {
#pragma unroll
        for (int c = 0; c < 8; c++) o[c] = (o[c] > 0.f) ? o[c] : expm1f(o[c]);
        uint4 p;
        p.x = (uint)f2bf(o[0]) | ((uint)f2bf(o[1]) << 16);
        p.y = (uint)f2bf(o[2]) | ((uint)f2bf(o[3]) << 16);
        p.z = (uint)f2bf(o[4]) | ((uint)f2bf(o[5]) << 16);
        p.w = (uint)f2bf(o[6]) | ((uint)f2bf(o[7]) << 16);
        *(uint4*)(out_bf + (long)i * DHID + c0) = p;
    } else {
        *(float4*)&out_f32[(long)i * DHID + c0]     = *(float4*)&o[0];
        *(float4*)&out_f32[(long)i * DHID + c0 + 4] = *(float4*)&o[4];
        // fused log_softmax over the 512-wide row held by this wave
        float mx = o[0];
#pragma unroll
        for (int c = 1; c < 8; c++) mx = fmaxf(mx, o[c]);
#pragma unroll
        for (int off = 1; off < 64; off <<= 1) mx = fmaxf(mx, __shfl_xor(mx, off));
        float se = 0.f;
#pragma unroll
        for (int c = 0; c < 8; c++) se += __expf(o[c] - mx);
#pragma unroll
        for (int off = 1; off < 64; off <<= 1) se += __shfl_xor(se, off);
        float lg = mx + logf(se);
        float l0[8];
#pragma unroll
        for (int c = 0; c < 8; c++) l0[c] = o[c] - lg;
        *(float4*)&out_lsm[(long)i * DHID + c0]     = *(float4*)&l0[0];
        *(float4*)&out_lsm[(long)i * DHID + c0 + 4] = *(float4*)&l0[4];
    }
}

// ---------------- launch (7 dispatches) ----------------

extern "C" void kernel_launch(void* const* d_in, const int* in_sizes, int n_in,
                              void* d_out, int out_size, void* d_ws, size_t ws_size,
                              hipStream_t stream) {
    const float* x     = (const float*)d_in[0];
    const int*   ei    = (const int*)d_in[1];
    const float* Wl1   = (const float*)d_in[2];
    const float* bl1   = (const float*)d_in[3];
    const float* Wr1   = (const float*)d_in[4];
    const float* br1   = (const float*)d_in[5];
    const float* att1  = (const float*)d_in[6];
    const float* bias1 = (const float*)d_in[7];
    const float* Wl2   = (const float*)d_in[8];
    const float* bl2   = (const float*)d_in[9];
    const float* Wr2   = (const float*)d_in[10];
    const float* br2   = (const float*)d_in[11];
    const float* att2  = (const float*)d_in[12];
    const float* bias2 = (const float*)d_in[13];

    float* out = (float*)d_out;
    float* h2  = out;                      // final layer-2 output [NN,512] f32
    float* lsm = out + (long)NN * DHID;    // log_softmax area

    ushort* lrbuf  = (ushort*)d_ws;                      // [NN,1024] bf16
    ushort* Abf    = lrbuf + (long)NN * NLR;             // [MPAD,512] bf16
    ushort* Wt1    = Abf + (long)MPAD * DHID;            // [1024,256] bf16
    ushort* Wt2    = Wt1 + (long)NLR * D_IN;             // [1024,512] bf16
    int*    csr_src = (int*)(Wt2 + (long)NLR * DHID);    // ET + CPAD
    int*    count   = csr_src + ET + CPAD;               // NN
    int*    offs    = count + NN;                        // NN+1
    int*    cursor  = offs + NN + 1;                     // NN

    const int* srcv = ei;
    const int* dstv = ei + NE;

    // K1: x->bf16 convert + pad zero || count init + csr pad
    k_prep<<<PREP_BLKS + INIT_BLKS, 256, 0, stream>>>(x, Abf, count, csr_src);
    // K2: degree histogram || both weight transposes
    k_hist_tw<<<HIST_BLKS + TW_BLKS, 256, 0, stream>>>(dstv, count, Wl1, Wr1, Wt1,
                                                       Wl2, Wr2, Wt2);
    // K3: exclusive scan -> offs, cursor
    scan_kernel<<<1, 1024, 0, stream>>>(count, offs, cursor);

    // K4: layer-1 GEMM || CSR scatter (overlapped)
    k_gemm_scatter<<<GEMM_BLKS + SCAT_BLKS, 256, 0, stream>>>(Abf, D_IN, Wt1, bl1, br1,
                                                              lrbuf, srcv, dstv, cursor, csr_src);
    // K5: layer-1 aggregate (+ELU) -> h1 (bf16, into Abf)
    aggregate_kernel<0><<<NN / 4, 256, 0, stream>>>(lrbuf, att1, bias1, csr_src, offs, Abf, nullptr, nullptr);

    // K6: layer-2 GEMM (no scatter blocks)
    k_gemm_scatter<<<GEMM_BLKS, 256, 0, stream>>>(Abf, DHID, Wt2, bl2, br2,
                                                  lrbuf, nullptr, nullptr, nullptr, nullptr);
    // K7: layer-2 aggregate + fused log_softmax
    aggregate_kernel<1><<<NN / 4, 256, 0, stream>>>(lrbuf, att2, bias2, csr_src, offs, nullptr, h2, lsm);
}